// Round 8
// baseline (149.068 us; speedup 1.0000x reference)
//
#include <hip/hip_runtime.h>
#include <hip/hip_bf16.h>

#define NFFT   4194304
#define NMODES 2
#define NTAPS  101
#define NVALID (NFFT - NTAPS + 1)   // 4194204
#define N0     (NTAPS / 2)          // 50

constexpr int BLOCK = 256;                          // 4 waves
constexpr int TILE  = 2048;                         // output samples per block (512/wave)
constexpr int NT    = (NVALID + TILE - 1) / TILE;   // 2048 blocks, one tile each
constexpr int WIN   = 2176;                         // staged P samples (max read idx 2151)
constexpr int NM    = 15;                           // banded MFMA accumulation steps
constexpr int TWRD  = 136;                          // words per rotated B table
constexpr int NTAB  = 8;                            // tables: r(4) x o(2)

typedef __attribute__((ext_vector_type(8)))  short short8;
typedef __attribute__((ext_vector_type(16))) float float16;
typedef __attribute__((ext_vector_type(4)))  unsigned uintv4;   // native vec for NT store

static __device__ __forceinline__ unsigned short f2bf(float x) {
    __hip_bfloat16 h = __float2bfloat16(x);
    return *reinterpret_cast<unsigned short*>(&h);
}
static __device__ __forceinline__ unsigned pk(float e0, float e1) {
    return (unsigned)f2bf(e0) | ((unsigned)f2bf(e1) << 16);
}
// XOR word bits 2..4 with word bits 5..7: bijective within each 32-word window,
// preserves 16B groups; spreads 64B-stride accesses across banks.
static __device__ __forceinline__ int swz(int s) {
    return s ^ (((s >> 5) & 7) << 2);
}

__global__ __launch_bounds__(BLOCK, 6) void nl_kernel(
    const float* __restrict__ xa,   // d_in[0] big stream (A = xr)
    const float* __restrict__ xb,   // d_in[1] big stream (B = xi)
    const float* __restrict__ W,  const float* __restrict__ b,
    const float* __restrict__ power, unsigned* __restrict__ out)
{
    // Union: phase1 = [Pl 0..2175 | Bt 2176..3263]; phase2 (after barrier) = Ph[0..4095].
    __shared__ __align__(16) unsigned lds[4096];     // 16 KB
    unsigned* const Pl = lds;
    unsigned* const Bt = lds + WIN;
    float*    const Ph = reinterpret_cast<float*>(lds);

    const int tid  = threadIdx.x;
    const int lane = tid & 63;
    const int wid  = tid >> 6;
    const int colc = lane & 31;      // B/C column = (c_s<<1)|o ; also A row index
    const int h    = lane >> 5;      // k half: k = 8h + e
    const int cs   = colc >> 1;      // fine shift 0..15
    const int o    = colc & 1;       // output mode
    const int r    = colc;           // A row

    const int tile_start = blockIdx.x * TILE;

    const float4* __restrict__ xa4 = reinterpret_cast<const float4*>(xa); // 2 samples
    const float4* __restrict__ xb4 = reinterpret_cast<const float4*>(xb);

    // ---- stage P = xa^2 + xb^2 as bf16x2 into swizzled LDS; depth-2 pipeline ----
    const float4 z4 = make_float4(0.f, 0.f, 0.f, 0.f);
    #define LDK(k, A, C) { const int g = tile_start + 2 * tid + 512 * (k);          \
        const bool v = (g < NFFT);                                                  \
        A = v ? xa4[g >> 1] : z4; C = v ? xb4[g >> 1] : z4; }
    #define STK(k, A, C) { const int s = 2 * tid + 512 * (k);                       \
        const unsigned u0 = pk(A.x * A.x + C.x * C.x, A.y * A.y + C.y * C.y);       \
        const unsigned u1 = pk(A.z * A.z + C.z * C.z, A.w * A.w + C.w * C.w);       \
        *reinterpret_cast<uint2*>(&Pl[swz(s)]) = make_uint2(u0, u1); }
    {
        float4 a0, c0, a1, c1;
        LDK(0, a0, c0); LDK(1, a1, c1);
        STK(0, a0, c0); LDK(2, a0, c0);
        STK(1, a1, c1); LDK(3, a1, c1);
        STK(2, a0, c0);
        const bool k4 = (2 * tid + 2048) < WIN;      // tid < 64
        float4 a4 = z4, c4 = z4;
        if (k4) LDK(4, a4, c4);
        STK(3, a1, c1);
        if (k4) STK(4, a4, c4);
    }
    #undef LDK
    #undef STK

    __builtin_amdgcn_sched_barrier(0);

    // ---- rotated B tables: Bt[(2r+o)*136 + 4q + d] = Bval(tau=4q+r+d, o) ----
    {
        const float4* __restrict__ Wt = reinterpret_cast<const float4*>(W);
        for (int idx = tid; idx < NTAB * TWRD; idx += BLOCK) {
            const int tab = idx / TWRD;
            const int w   = idx - tab * TWRD;
            const int rr  = tab >> 1, oo = tab & 1;
            const int t   = (w & ~3) + rr + (w & 3) - 15;   // tau - 15
            const bool ok = (unsigned)t <= 100u;
            const float4 ww = Wt[ok ? t : 0];
            Bt[idx] = ok ? pk(oo ? ww.y : ww.x, oo ? ww.w : ww.z) : 0u;
        }
    }
    __builtin_amdgcn_sched_barrier(0);
    __syncthreads();

    // ---- per-wave 512-sample chunk: 15 x (b128 A + b128 B + 32x32x16 MFMA) ----
    const int cb   = wid * 512;
    const int tau0 = 4 * h - cs + 15;                 // in [0,19]
    const int tb   = (((tau0 & 3) << 1) | o) * TWRD + (tau0 >> 2) * 4;
    float16 acc = {};
    uint4 areg[4];                    // 4-deep A prefetch pipe (static idx post-unroll)
    #pragma unroll
    for (int m = 0; m < 4; ++m)
        areg[m] = *reinterpret_cast<const uint4*>(&Pl[swz(cb + 16 * r + 8 * m + 4 * h)]);
    #pragma unroll
    for (int m = 0; m < NM; ++m) {
        const uint4 bq = *reinterpret_cast<const uint4*>(&Bt[tb + 8 * m]);
        acc = __builtin_amdgcn_mfma_f32_32x32x16_bf16(
                  __builtin_bit_cast(short8, areg[m & 3]),
                  __builtin_bit_cast(short8, bq), acc, 0, 0, 0);
        if (m + 4 < NM)
            areg[m & 3] = *reinterpret_cast<const uint4*>(
                              &Pl[swz(cb + 16 * r + 8 * (m + 4) + 4 * h)]);
    }

    // ---- issue epilogue global loads EARLY (hide L2 latency under phi barriers) ----
    const int base  = tile_start + 8 * tid;           // this thread's 8 output samples
    const bool full = (blockIdx.x != NT - 1);
    float4 A0, A1, A2, A3, B0, B1, B2, B3;
    if (full) {
        const float4* __restrict__ pa = xa4 + ((base + N0) >> 1);
        const float4* __restrict__ pb = xb4 + ((base + N0) >> 1);
        A0 = pa[0]; A1 = pa[1]; A2 = pa[2]; A3 = pa[3];
        B0 = pb[0]; B1 = pb[1]; B2 = pb[2]; B3 = pb[3];
    }

    // ---- phi scatter into LDS per C/D layout (bias folded in) ----
    // C/D: col = lane&31, row = (reg&3) + 8*(reg>>2) + 4*(lane>>5);
    // word w = 2*local_sample + o = wid*1024 + 32*row + colc (conflict-free with swz).
    const float bo = o ? b[1] : b[0];
    __syncthreads();                  // Pl/Bt dead -> safe to alias Ph
    #pragma unroll
    for (int j = 0; j < 16; ++j) {
        const int row = (j & 3) + 8 * (j >> 2) + 4 * h;
        Ph[swz(wid * 1024 + 32 * row + colc)] = acc[j] + bo;
    }
    __syncthreads();

    // ---- gather phi for 8 consecutive samples: 4 x ds_read_b128 ----
    const float coef = 0.066268f * exp10f(power[0] * 0.1f);
    const float4 f0 = *reinterpret_cast<const float4*>(&Ph[swz(16 * tid +  0)]);
    const float4 f1 = *reinterpret_cast<const float4*>(&Ph[swz(16 * tid +  4)]);
    const float4 f2 = *reinterpret_cast<const float4*>(&Ph[swz(16 * tid +  8)]);
    const float4 f3 = *reinterpret_cast<const float4*>(&Ph[swz(16 * tid + 12)]);

    uintv4* __restrict__ out4 = reinterpret_cast<uintv4*>(out);

    if (full) {
        #define EPI(q, F, A, B) {                                                   \
            float s00, c00, s01, c01, s10, c10, s11, c11;                           \
            __sincosf(F.x * coef, &s00, &c00);                                      \
            __sincosf(F.y * coef, &s01, &c01);                                      \
            __sincosf(F.z * coef, &s10, &c10);                                      \
            __sincosf(F.w * coef, &s11, &c11);                                      \
            uintv4 ov;                                                              \
            ov.x = pk(B.x * c00 - A.x * s00, A.x * c00 + B.x * s00);                \
            ov.y = pk(B.y * c01 - A.y * s01, A.y * c01 + B.y * s01);                \
            ov.z = pk(B.z * c10 - A.z * s10, A.z * c10 + B.z * s10);                \
            ov.w = pk(B.w * c11 - A.w * s11, A.w * c11 + B.w * s11);                \
            __builtin_nontemporal_store(ov, &out4[(base >> 1) + (q)]); }
        EPI(0, f0, A0, B0)
        EPI(1, f1, A1, B1)
        EPI(2, f2, A2, B2)
        EPI(3, f3, A3, B3)
        #undef EPI
    } else {
        const float2* __restrict__ xa2 = reinterpret_cast<const float2*>(xa);
        const float2* __restrict__ xb2 = reinterpret_cast<const float2*>(xb);
        #define TEPI(q, p0v, p1v, p2v, p3v) {                                       \
            const int n0v = base + 2 * (q);                                         \
            if (n0v < NVALID) {                                                     \
                const float2 Av = xa2[n0v + N0]; const float2 Bv = xb2[n0v + N0];   \
                float s0, c0v, s1, c1v;                                             \
                __sincosf((p0v) * coef, &s0, &c0v);                                 \
                __sincosf((p1v) * coef, &s1, &c1v);                                 \
                uint2 ov;                                                           \
                ov.x = pk(Bv.x * c0v - Av.x * s0, Av.x * c0v + Bv.x * s0);          \
                ov.y = pk(Bv.y * c1v - Av.y * s1, Av.y * c1v + Bv.y * s1);          \
                reinterpret_cast<uint2*>(out)[n0v] = ov; }                          \
            const int n1v = base + 2 * (q) + 1;                                     \
            if (n1v < NVALID) {                                                     \
                const float2 Av = xa2[n1v + N0]; const float2 Bv = xb2[n1v + N0];   \
                float s0, c0v, s1, c1v;                                             \
                __sincosf((p2v) * coef, &s0, &c0v);                                 \
                __sincosf((p3v) * coef, &s1, &c1v);                                 \
                uint2 ov;                                                           \
                ov.x = pk(Bv.x * c0v - Av.x * s0, Av.x * c0v + Bv.x * s0);          \
                ov.y = pk(Bv.y * c1v - Av.y * s1, Av.y * c1v + Bv.y * s1);          \
                reinterpret_cast<uint2*>(out)[n1v] = ov; } }
        TEPI(0, f0.x, f0.y, f0.z, f0.w)
        TEPI(1, f1.x, f1.y, f1.z, f1.w)
        TEPI(2, f2.x, f2.y, f2.z, f2.w)
        TEPI(3, f3.x, f3.y, f3.z, f3.w)
        #undef TEPI
    }
}

extern "C" void kernel_launch(void* const* d_in, const int* in_sizes, int n_in,
                              void* d_out, int out_size, void* d_ws, size_t ws_size,
                              hipStream_t stream) {
    // Bind by size (robust): big arrays = x streams, 404 = W, 2 = b, 1 = power.
    const float* big[2] = {nullptr, nullptr};
    const float* W = nullptr; const float* b = nullptr; const float* power = nullptr;
    int nbig = 0;
    for (int i = 0; i < n_in; ++i) {
        const float* p = (const float*)d_in[i];
        const int sz = in_sizes[i];
        if (sz == NFFT * NMODES)       { if (nbig < 2) big[nbig++] = p; }
        else if (sz == NTAPS * NMODES * NMODES) { W = p; }
        else if (sz == NMODES)         { b = p; }
        else if (sz == 1)              { power = p; }
    }

    unsigned* out = (unsigned*)d_out;
    nl_kernel<<<NT, BLOCK, 0, stream>>>(big[0], big[1], W, b, power, out);
}

// Round 9
// 144.499 us; speedup vs baseline: 1.0316x; 1.0316x over previous
//
#include <hip/hip_runtime.h>
#include <hip/hip_bf16.h>

#define NFFT   4194304
#define NMODES 2
#define NTAPS  101
#define NVALID (NFFT - NTAPS + 1)   // 4194204
#define N0     (NTAPS / 2)          // 50

constexpr int BLOCK = 256;                          // 4 waves
constexpr int TILE  = 2048;                         // output samples per block (512/wave)
constexpr int NT    = (NVALID + TILE - 1) / TILE;   // 2048 blocks, one tile each
constexpr int WIN   = 2176;                         // staged P samples (max read idx 2151)
constexpr int NM    = 15;                           // banded MFMA accumulation steps
constexpr int TBW   = 272;                          // compact B-table words

typedef __attribute__((ext_vector_type(8)))  short short8;
typedef __attribute__((ext_vector_type(16))) float float16;
typedef __attribute__((ext_vector_type(4)))  unsigned uintv4;   // native vec for NT store

static __device__ __forceinline__ unsigned short f2bf(float x) {
    __hip_bfloat16 h = __float2bfloat16(x);
    return *reinterpret_cast<unsigned short*>(&h);
}
static __device__ __forceinline__ unsigned pk(float e0, float e1) {
    return (unsigned)f2bf(e0) | ((unsigned)f2bf(e1) << 16);
}
// XOR word bits 2..4 with word bits 5..7: bijective, preserves aligned 4-word groups,
// spreads 64B-stride accesses across banks (residual 2-way = free).
static __device__ __forceinline__ int swz(int s) {
    return s ^ (((s >> 5) & 7) << 2);
}

__global__ __launch_bounds__(BLOCK, 8) void nl_kernel(
    const float* __restrict__ xa,   // d_in[0] big stream (A = xr)
    const float* __restrict__ xb,   // d_in[1] big stream (B = xi)
    const float* __restrict__ W,  const float* __restrict__ b,
    const float* __restrict__ power, unsigned* __restrict__ out)
{
    // Phase 1: [Pl 0..2175 | Bt 2176..2447]; Phase 2 (after barrier): Ph[0..4095].
    __shared__ __align__(16) unsigned lds[4096];     // 16 KB
    unsigned* const Pl = lds;
    unsigned* const Bt = lds + WIN;
    float*    const Ph = reinterpret_cast<float*>(lds);

    const int tid  = threadIdx.x;
    const int lane = tid & 63;
    const int wid  = tid >> 6;
    const int colc = lane & 31;      // B/C column = (c_s<<1)|o ; also A row index
    const int h    = lane >> 5;      // k half: k = 8h + e
    const int cs   = colc >> 1;      // fine shift 0..15
    const int o    = colc & 1;       // output mode
    const int r    = colc;           // A row

    const int tile_start = blockIdx.x * TILE;

    // ---- stage P = xa^2 + xb^2 as bf16x2 into swizzled LDS (R5-verified) ----
    const float4* __restrict__ xa4 = reinterpret_cast<const float4*>(xa); // 2 samples
    const float4* __restrict__ xb4 = reinterpret_cast<const float4*>(xb);
    #pragma unroll
    for (int k = 0; k < 5; ++k) {
        const int s = 2 * tid + 512 * k;            // even
        if (k < 4 || s < WIN) {
            const int g = tile_start + s;
            float4 a = make_float4(0.f, 0.f, 0.f, 0.f), c = a;
            if (g < NFFT) { a = xa4[g >> 1]; c = xb4[g >> 1]; }
            const unsigned u0 = pk(a.x * a.x + c.x * c.x, a.y * a.y + c.y * c.y);
            const unsigned u1 = pk(a.z * a.z + c.z * c.z, a.w * a.w + c.w * c.w);
            *reinterpret_cast<uint2*>(&Pl[swz(s)]) = make_uint2(u0, u1);
        }
    }

    __builtin_amdgcn_sched_barrier(0);

    // ---- compact B table: Bt[(t+15)*2 + o] = pk(W[t,0,o], W[t,1,o]) ----
    {
        const float4* __restrict__ Wt = reinterpret_cast<const float4*>(W);
        #pragma unroll
        for (int idx = tid; idx < TBW; idx += BLOCK) {
            const int t  = (idx >> 1) - 15;
            const int oo = idx & 1;
            const bool ok = (unsigned)t <= 100u;
            const float4 w = Wt[ok ? t : 0];
            Bt[idx] = ok ? pk(oo ? w.y : w.x, oo ? w.w : w.z) : 0u;
        }
    }
    __builtin_amdgcn_sched_barrier(0);
    __syncthreads();

    // ---- per-wave 512-sample chunk: 15 x (b128 A + 4x b32 B + 32x32x16 MFMA) ----
    const int cb    = wid * 512;
    const int bbase = ((4 * h - cs + 15) << 1) | o;
    float16 acc = {};
    uint4 areg[4];                    // 4-deep A prefetch pipe (static idx post-unroll)
    #pragma unroll
    for (int m = 0; m < 4; ++m)
        areg[m] = *reinterpret_cast<const uint4*>(&Pl[swz(cb + 16 * r + 8 * m + 4 * h)]);
    #pragma unroll
    for (int m = 0; m < NM; ++m) {
        uint4 bq;
        bq.x = Bt[bbase + 16 * m + 0];
        bq.y = Bt[bbase + 16 * m + 2];
        bq.z = Bt[bbase + 16 * m + 4];
        bq.w = Bt[bbase + 16 * m + 6];
        acc = __builtin_amdgcn_mfma_f32_32x32x16_bf16(
                  __builtin_bit_cast(short8, areg[m & 3]),
                  __builtin_bit_cast(short8, bq), acc, 0, 0, 0);
        if (m + 4 < NM)
            areg[m & 3] = *reinterpret_cast<const uint4*>(
                              &Pl[swz(cb + 16 * r + 8 * (m + 4) + 4 * h)]);
    }

    // ---- phi scatter into LDS per C/D layout (bias folded in) ----
    // C/D: col = lane&31, row = (reg&3) + 8*(reg>>2) + 4*(lane>>5);
    // word w = 2*local_sample + o = wid*1024 + 32*row + colc (2-way max with swz).
    const float bo = o ? b[1] : b[0];
    __syncthreads();                  // Pl/Bt dead -> safe to alias Ph
    #pragma unroll
    for (int j = 0; j < 16; ++j) {
        const int row = (j & 3) + 8 * (j >> 2) + 4 * h;
        Ph[swz(wid * 1024 + 32 * row + colc)] = acc[j] + bo;
    }
    __syncthreads();

    // ---- gather phi for 8 consecutive samples: 4 x ds_read_b128 (named regs) ----
    const float coef = 0.066268f * exp10f(power[0] * 0.1f);
    const float4 f0 = *reinterpret_cast<const float4*>(&Ph[swz(16 * tid +  0)]);
    const float4 f1 = *reinterpret_cast<const float4*>(&Ph[swz(16 * tid +  4)]);
    const float4 f2 = *reinterpret_cast<const float4*>(&Ph[swz(16 * tid +  8)]);
    const float4 f3 = *reinterpret_cast<const float4*>(&Ph[swz(16 * tid + 12)]);

    const int base = tile_start + 8 * tid;            // this thread's 8 output samples
    uintv4* __restrict__ out4 = reinterpret_cast<uintv4*>(out);

    if (blockIdx.x != NT - 1) {                       // full tile: branch-free
        // x loaded AT USE (no cross-barrier liveness -> no spills)
        #define EPI(q, F) {                                                         \
            const float4 A = xa4[((base + N0) >> 1) + (q)];                         \
            const float4 B = xb4[((base + N0) >> 1) + (q)];                         \
            float s00, c00, s01, c01, s10, c10, s11, c11;                           \
            __sincosf(F.x * coef, &s00, &c00);                                      \
            __sincosf(F.y * coef, &s01, &c01);                                      \
            __sincosf(F.z * coef, &s10, &c10);                                      \
            __sincosf(F.w * coef, &s11, &c11);                                      \
            uintv4 ov;                                                              \
            ov.x = pk(B.x * c00 - A.x * s00, A.x * c00 + B.x * s00);                \
            ov.y = pk(B.y * c01 - A.y * s01, A.y * c01 + B.y * s01);                \
            ov.z = pk(B.z * c10 - A.z * s10, A.z * c10 + B.z * s10);                \
            ov.w = pk(B.w * c11 - A.w * s11, A.w * c11 + B.w * s11);                \
            __builtin_nontemporal_store(ov, &out4[(base >> 1) + (q)]); }
        EPI(0, f0)
        EPI(1, f1)
        EPI(2, f2)
        EPI(3, f3)
        #undef EPI
    } else {                                          // tail tile: guarded
        const float2* __restrict__ xa2 = reinterpret_cast<const float2*>(xa);
        const float2* __restrict__ xb2 = reinterpret_cast<const float2*>(xb);
        #define TEPI(q, p0v, p1v, p2v, p3v) {                                       \
            const int n0v = base + 2 * (q);                                         \
            if (n0v < NVALID) {                                                     \
                const float2 Av = xa2[n0v + N0]; const float2 Bv = xb2[n0v + N0];   \
                float s0, c0v, s1, c1v;                                             \
                __sincosf((p0v) * coef, &s0, &c0v);                                 \
                __sincosf((p1v) * coef, &s1, &c1v);                                 \
                uint2 ov;                                                           \
                ov.x = pk(Bv.x * c0v - Av.x * s0, Av.x * c0v + Bv.x * s0);          \
                ov.y = pk(Bv.y * c1v - Av.y * s1, Av.y * c1v + Bv.y * s1);          \
                reinterpret_cast<uint2*>(out)[n0v] = ov; }                          \
            const int n1v = base + 2 * (q) + 1;                                     \
            if (n1v < NVALID) {                                                     \
                const float2 Av = xa2[n1v + N0]; const float2 Bv = xb2[n1v + N0];   \
                float s0, c0v, s1, c1v;                                             \
                __sincosf((p2v) * coef, &s0, &c0v);                                 \
                __sincosf((p3v) * coef, &s1, &c1v);                                 \
                uint2 ov;                                                           \
                ov.x = pk(Bv.x * c0v - Av.x * s0, Av.x * c0v + Bv.x * s0);          \
                ov.y = pk(Bv.y * c1v - Av.y * s1, Av.y * c1v + Bv.y * s1);          \
                reinterpret_cast<uint2*>(out)[n1v] = ov; } }
        TEPI(0, f0.x, f0.y, f0.z, f0.w)
        TEPI(1, f1.x, f1.y, f1.z, f1.w)
        TEPI(2, f2.x, f2.y, f2.z, f2.w)
        TEPI(3, f3.x, f3.y, f3.z, f3.w)
        #undef TEPI
    }
}

extern "C" void kernel_launch(void* const* d_in, const int* in_sizes, int n_in,
                              void* d_out, int out_size, void* d_ws, size_t ws_size,
                              hipStream_t stream) {
    // Bind by size (robust): big arrays = x streams, 404 = W, 2 = b, 1 = power.
    const float* big[2] = {nullptr, nullptr};
    const float* W = nullptr; const float* b = nullptr; const float* power = nullptr;
    int nbig = 0;
    for (int i = 0; i < n_in; ++i) {
        const float* p = (const float*)d_in[i];
        const int sz = in_sizes[i];
        if (sz == NFFT * NMODES)       { if (nbig < 2) big[nbig++] = p; }
        else if (sz == NTAPS * NMODES * NMODES) { W = p; }
        else if (sz == NMODES)         { b = p; }
        else if (sz == 1)              { power = p; }
    }

    unsigned* out = (unsigned*)d_out;
    nl_kernel<<<NT, BLOCK, 0, stream>>>(big[0], big[1], W, b, power, out);
}

// Round 10
// 124.272 us; speedup vs baseline: 1.1995x; 1.1628x over previous
//
#include <hip/hip_runtime.h>
#include <hip/hip_bf16.h>

#define NFFT   4194304
#define NMODES 2
#define NTAPS  101
#define NVALID (NFFT - NTAPS + 1)   // 4194204
#define N0     (NTAPS / 2)          // 50

constexpr int BLOCK = 256;                          // 4 fully-independent waves
constexpr int WTILE = 512;                          // output samples per wave
constexpr int TILE  = 2048;                         // per block (4 waves)
constexpr int NT    = (NVALID + TILE - 1) / TILE;   // 2048 blocks
constexpr int WWIN  = 640;                          // staged P words per wave (max idx 615)
constexpr int NM    = 15;                           // banded MFMA accumulation steps
constexpr int TBW   = 272;                          // compact B-table words per wave
constexpr int WLDS  = WWIN + TBW;                   // 912 words per wave slice

typedef __attribute__((ext_vector_type(8)))  short short8;
typedef __attribute__((ext_vector_type(16))) float float16;

static __device__ __forceinline__ unsigned short f2bf(float x) {
    __hip_bfloat16 h = __float2bfloat16(x);
    return *reinterpret_cast<unsigned short*>(&h);
}
static __device__ __forceinline__ unsigned pk(float e0, float e1) {
    return (unsigned)f2bf(e0) | ((unsigned)f2bf(e1) << 16);
}
// XOR word bits 2..4 with word bits 5..7: bijective, preserves aligned 4-word groups,
// spreads 64B-stride accesses across banks (residual 2-way = free).
static __device__ __forceinline__ int swz(int s) {
    return s ^ (((s >> 5) & 7) << 2);
}

__global__ __launch_bounds__(BLOCK, 8) void nl_kernel(
    const float* __restrict__ xa,   // d_in[0] big stream (A = xr)
    const float* __restrict__ xb,   // d_in[1] big stream (B = xi)
    const float* __restrict__ W,  const float* __restrict__ b,
    const float* __restrict__ power, unsigned* __restrict__ out)
{
    // Per-wave private slices -> NO __syncthreads anywhere in this kernel.
    // Wave slice: [Pl 0..639 | Bt 640..911]. 4 slices = 14.6 KB/block.
    __shared__ __align__(16) unsigned lds[4 * WLDS];

    const int tid  = threadIdx.x;
    const int lane = tid & 63;
    const int wid  = tid >> 6;
    const int colc = lane & 31;      // B/C column = (c_s<<1)|o ; also A row index
    const int h    = lane >> 5;      // k half: k = 8h + e
    const int cs   = colc >> 1;      // fine shift 0..15
    const int o    = colc & 1;       // output mode
    const int r    = colc;           // A row

    unsigned* const Pl = lds + wid * WLDS;
    unsigned* const Bt = Pl + WWIN;

    const int wstart = blockIdx.x * TILE + wid * WTILE;   // wave's first output sample

    // ---- stage P = xa^2 + xb^2 as bf16x2 into this wave's swizzled slice ----
    const float4* __restrict__ xa4 = reinterpret_cast<const float4*>(xa); // 2 samples
    const float4* __restrict__ xb4 = reinterpret_cast<const float4*>(xb);
    #pragma unroll
    for (int k = 0; k < 5; ++k) {
        const int s = 2 * lane + 128 * k;           // even, covers 0..639 exactly
        const int g = wstart + s;
        float4 a = make_float4(0.f, 0.f, 0.f, 0.f), c = a;
        if (g < NFFT) { a = xa4[g >> 1]; c = xb4[g >> 1]; }
        const unsigned u0 = pk(a.x * a.x + c.x * c.x, a.y * a.y + c.y * c.y);
        const unsigned u1 = pk(a.z * a.z + c.z * c.z, a.w * a.w + c.w * c.w);
        *reinterpret_cast<uint2*>(&Pl[swz(s)]) = make_uint2(u0, u1);
    }

    __builtin_amdgcn_sched_barrier(0);

    // ---- compact B table (per wave): Bt[(t+15)*2 + o] = pk(W[t,0,o], W[t,1,o]) ----
    {
        const float4* __restrict__ Wt = reinterpret_cast<const float4*>(W);
        #pragma unroll
        for (int idx = lane; idx < TBW; idx += 64) {
            const int t  = (idx >> 1) - 15;
            const int oo = idx & 1;
            const bool ok = (unsigned)t <= 100u;
            const float4 w = Wt[ok ? t : 0];
            Bt[idx] = ok ? pk(oo ? w.y : w.x, oo ? w.w : w.z) : 0u;
        }
    }
    __builtin_amdgcn_sched_barrier(0);
    // No barrier: wave-private LDS; in-order lgkmcnt ordering suffices.

    // ---- 512-sample chunk: 15 x (b128 A + 4x b32 B + 32x32x16 MFMA) ----
    const int bbase = ((4 * h - cs + 15) << 1) | o;
    float16 acc = {};
    uint4 areg[4];                    // 4-deep A prefetch pipe (static idx post-unroll)
    #pragma unroll
    for (int m = 0; m < 4; ++m)
        areg[m] = *reinterpret_cast<const uint4*>(&Pl[swz(16 * r + 8 * m + 4 * h)]);
    #pragma unroll
    for (int m = 0; m < NM; ++m) {
        uint4 bq;
        bq.x = Bt[bbase + 16 * m + 0];
        bq.y = Bt[bbase + 16 * m + 2];
        bq.z = Bt[bbase + 16 * m + 4];
        bq.w = Bt[bbase + 16 * m + 6];
        acc = __builtin_amdgcn_mfma_f32_32x32x16_bf16(
                  __builtin_bit_cast(short8, areg[m & 3]),
                  __builtin_bit_cast(short8, bq), acc, 0, 0, 0);
        if (m + 4 < NM)
            areg[m & 3] = *reinterpret_cast<const uint4*>(
                              &Pl[swz(16 * r + 8 * (m + 4) + 4 * h)]);
    }

    // ---- epilogue: straight from accumulators (R5-verified clean form) ----
    // C/D: col = lane&31, row = (reg&3) + 8*(reg>>2) + 4*(lane>>5);
    // out-word idx = 2*(wstart + 16*row + cs) + o -> per j the wave covers two
    // full 128B segments: coalesced dwords.
    const float bo   = o ? b[1] : b[0];
    const float coef = 0.066268f * exp10f(power[0] * 0.1f);

    if (blockIdx.x != NT - 1) {                       // full tile: branch-free
        #pragma unroll
        for (int j = 0; j < 16; ++j) {
            const int row = (j & 3) + 8 * (j >> 2) + 4 * h;
            const int n   = wstart + 16 * row + cs;
            const float Ax = xa[(n + N0) * 2 + o];
            const float Bx = xb[(n + N0) * 2 + o];
            float sn, cn;
            __sincosf((acc[j] + bo) * coef, &sn, &cn);
            __builtin_nontemporal_store(pk(Bx * cn - Ax * sn, Ax * cn + Bx * sn),
                                        &out[n * 2 + o]);
        }
    } else {                                          // tail tile: guarded
        #pragma unroll
        for (int j = 0; j < 16; ++j) {
            const int row = (j & 3) + 8 * (j >> 2) + 4 * h;
            const int n   = wstart + 16 * row + cs;
            if (n < NVALID) {
                const float Ax = xa[(n + N0) * 2 + o];
                const float Bx = xb[(n + N0) * 2 + o];
                float sn, cn;
                __sincosf((acc[j] + bo) * coef, &sn, &cn);
                __builtin_nontemporal_store(pk(Bx * cn - Ax * sn, Ax * cn + Bx * sn),
                                            &out[n * 2 + o]);
            }
        }
    }
}

extern "C" void kernel_launch(void* const* d_in, const int* in_sizes, int n_in,
                              void* d_out, int out_size, void* d_ws, size_t ws_size,
                              hipStream_t stream) {
    // Bind by size (robust): big arrays = x streams, 404 = W, 2 = b, 1 = power.
    const float* big[2] = {nullptr, nullptr};
    const float* W = nullptr; const float* b = nullptr; const float* power = nullptr;
    int nbig = 0;
    for (int i = 0; i < n_in; ++i) {
        const float* p = (const float*)d_in[i];
        const int sz = in_sizes[i];
        if (sz == NFFT * NMODES)       { if (nbig < 2) big[nbig++] = p; }
        else if (sz == NTAPS * NMODES * NMODES) { W = p; }
        else if (sz == NMODES)         { b = p; }
        else if (sz == 1)              { power = p; }
    }

    unsigned* out = (unsigned*)d_out;
    nl_kernel<<<NT, BLOCK, 0, stream>>>(big[0], big[1], W, b, power, out);
}

// Round 11
// 112.806 us; speedup vs baseline: 1.3215x; 1.1016x over previous
//
#include <hip/hip_runtime.h>
#include <hip/hip_bf16.h>

#define NFFT   4194304
#define NMODES 2
#define NTAPS  101
#define NVALID (NFFT - NTAPS + 1)   // 4194204
#define N0     (NTAPS / 2)          // 50

constexpr int BLOCK = 256;                          // 4 waves
constexpr int TILE  = 2048;                         // output samples per block
constexpr int NT    = (NVALID + TILE - 1) / TILE;   // 2048 blocks
constexpr int WIN   = 2176;                         // staged P samples (max read idx 2151)
constexpr int NCH   = WIN / 2;                      // 1088 16B chunks per x array
constexpr int NM    = 15;                           // banded MFMA accumulation steps
constexpr int TBW   = 272;                          // compact B-table words

// LDS word layout: xaR[0..4351] | xbR[4352..8703] | Pl[8704..10879] | Bt[10880..11151]
constexpr int OXA = 0;
constexpr int OXB = 4352;
constexpr int OPL = 8704;
constexpr int OBT = 10880;
constexpr int LWORDS = 11152;                       // 44608 B -> 3 blocks/CU

typedef __attribute__((ext_vector_type(8)))  short short8;
typedef __attribute__((ext_vector_type(16))) float float16;

static __device__ __forceinline__ unsigned short f2bf(float x) {
    __hip_bfloat16 h = __float2bfloat16(x);
    return *reinterpret_cast<unsigned short*>(&h);
}
static __device__ __forceinline__ unsigned pk(float e0, float e1) {
    return (unsigned)f2bf(e0) | ((unsigned)f2bf(e1) << 16);
}
// XOR word bits 2..4 with word bits 5..7: bijective, preserves aligned 4-word groups,
// spreads 64B-stride accesses across banks (residual 2-way = free).
static __device__ __forceinline__ int swz(int s) {
    return s ^ (((s >> 5) & 7) << 2);
}
// HBM -> LDS direct (16B/lane, no VGPR round trip). Dest must be linear:
// this lane's pointer == wave-uniform base + lane*16 (holds for c = uniform + lane).
static __device__ __forceinline__ void gl16(const float4* g, unsigned* l) {
    __builtin_amdgcn_global_load_lds(
        (const __attribute__((address_space(1))) void*)g,
        (__attribute__((address_space(3))) void*)l, 16, 0, 0);
}

__global__ __launch_bounds__(BLOCK, 3) void nl_kernel(
    const float* __restrict__ xa,   // d_in[0] big stream (A = xr)
    const float* __restrict__ xb,   // d_in[1] big stream (B = xi)
    const float* __restrict__ W,  const float* __restrict__ b,
    const float* __restrict__ power, unsigned* __restrict__ out)
{
    __shared__ __align__(16) unsigned lds[LWORDS];
    unsigned* const xaR = lds + OXA;
    unsigned* const xbR = lds + OXB;
    unsigned* const Pl  = lds + OPL;
    unsigned* const Bt  = lds + OBT;

    const int tid  = threadIdx.x;
    const int lane = tid & 63;
    const int wid  = tid >> 6;
    const int colc = lane & 31;      // B/C column = (c_s<<1)|o ; also A row index
    const int h    = lane >> 5;      // k half: k = 8h + e
    const int cs   = colc >> 1;      // fine shift 0..15
    const int o    = colc & 1;       // output mode
    const int r    = colc;           // A row

    const int tile_start = blockIdx.x * TILE;
    const int ts2        = tile_start >> 1;

    // ---- 1) async stage raw xa/xb -> LDS: deep vmcnt queue, zero VGPR cost ----
    const float4* __restrict__ xa4 = reinterpret_cast<const float4*>(xa); // 2 samples
    const float4* __restrict__ xb4 = reinterpret_cast<const float4*>(xb);
    #pragma unroll
    for (int k = 0; k < 4; ++k) {
        const int c  = tid + 256 * k;                // chunk = uniform + lane
        const int cc = min(ts2 + c, NFFT / 2 - 1);   // clamp OOB (zeroed in P-compute)
        gl16(xa4 + cc, &xaR[4 * c]);
        gl16(xb4 + cc, &xbR[4 * c]);
    }
    if (tid < 64) {                                  // wave 0: chunks 1024..1087
        const int c  = tid + 1024;
        const int cc = min(ts2 + c, NFFT / 2 - 1);
        gl16(xa4 + cc, &xaR[4 * c]);
        gl16(xb4 + cc, &xbR[4 * c]);
    }

    __builtin_amdgcn_sched_barrier(0);

    // ---- compact B table: Bt[(t+15)*2 + o] = pk(W[t,0,o], W[t,1,o]) ----
    {
        const float4* __restrict__ Wt = reinterpret_cast<const float4*>(W);
        #pragma unroll
        for (int idx = tid; idx < TBW; idx += BLOCK) {
            const int t  = (idx >> 1) - 15;
            const int oo = idx & 1;
            const bool ok = (unsigned)t <= 100u;
            const float4 w = Wt[ok ? t : 0];
            Bt[idx] = ok ? pk(oo ? w.y : w.x, oo ? w.w : w.z) : 0u;
        }
    }
    __syncthreads();     // drains vmcnt(0): raw tiles + Bt visible to whole block

    // ---- 2) P = xa^2 + xb^2 -> bf16x2 swizzled Pl (LDS -> LDS through regs) ----
    #pragma unroll
    for (int k = 0; k < 5; ++k) {
        const int tp = tid + 256 * k;                // sample-pair index
        if (k < 4 || tp < NCH) {
            const float4 a = *reinterpret_cast<const float4*>(&xaR[4 * tp]);
            const float4 c = *reinterpret_cast<const float4*>(&xbR[4 * tp]);
            const int g = tile_start + 2 * tp;       // even; g and g+1 valid together
            unsigned u0 = 0u, u1 = 0u;
            if (g < NFFT) {
                u0 = pk(a.x * a.x + c.x * c.x, a.y * a.y + c.y * c.y);
                u1 = pk(a.z * a.z + c.z * c.z, a.w * a.w + c.w * c.w);
            }
            *reinterpret_cast<uint2*>(&Pl[swz(2 * tp)]) = make_uint2(u0, u1);
        }
    }
    __syncthreads();

    // ---- 3) per-wave 512-sample chunk: 15 x (b128 A + 4x b32 B + MFMA) ----
    const int cb    = wid * 512;
    const int bbase = ((4 * h - cs + 15) << 1) | o;
    float16 acc = {};
    uint4 areg[4];                    // 4-deep A prefetch pipe (static idx post-unroll)
    #pragma unroll
    for (int m = 0; m < 4; ++m)
        areg[m] = *reinterpret_cast<const uint4*>(&Pl[swz(cb + 16 * r + 8 * m + 4 * h)]);
    #pragma unroll
    for (int m = 0; m < NM; ++m) {
        uint4 bq;
        bq.x = Bt[bbase + 16 * m + 0];
        bq.y = Bt[bbase + 16 * m + 2];
        bq.z = Bt[bbase + 16 * m + 4];
        bq.w = Bt[bbase + 16 * m + 6];
        acc = __builtin_amdgcn_mfma_f32_32x32x16_bf16(
                  __builtin_bit_cast(short8, areg[m & 3]),
                  __builtin_bit_cast(short8, bq), acc, 0, 0, 0);
        if (m + 4 < NM)
            areg[m & 3] = *reinterpret_cast<const uint4*>(
                              &Pl[swz(cb + 16 * r + 8 * (m + 4) + 4 * h)]);
    }

    // ---- 4) epilogue: direct from accumulators; x re-read from LDS raw copy ----
    // C/D: col = lane&31, row = (reg&3) + 8*(reg>>2) + 4*(lane>>5).
    // local x word = 2*(cb + 16*row + cs + N0) + o, max 4195 < 4352: always staged.
    // Half-waves read 32-word runs 128 words apart -> same banks -> 2-way = free.
    const float bo   = o ? b[1] : b[0];
    const float coef = 0.066268f * exp10f(power[0] * 0.1f);
    const float* __restrict__ xaF = reinterpret_cast<const float*>(xaR);
    const float* __restrict__ xbF = reinterpret_cast<const float*>(xbR);

    if (blockIdx.x != NT - 1) {                       // full tile: branch-free
        #pragma unroll
        for (int j = 0; j < 16; ++j) {
            const int row = (j & 3) + 8 * (j >> 2) + 4 * h;
            const int lw  = 2 * (cb + 16 * row + cs + N0) + o;
            const float Ax = xaF[lw];
            const float Bx = xbF[lw];
            float sn, cn;
            __sincosf((acc[j] + bo) * coef, &sn, &cn);
            const int n = tile_start + cb + 16 * row + cs;
            __builtin_nontemporal_store(pk(Bx * cn - Ax * sn, Ax * cn + Bx * sn),
                                        &out[n * 2 + o]);
        }
    } else {                                          // tail tile: guarded stores
        #pragma unroll
        for (int j = 0; j < 16; ++j) {
            const int row = (j & 3) + 8 * (j >> 2) + 4 * h;
            const int n   = tile_start + cb + 16 * row + cs;
            if (n < NVALID) {
                const int lw  = 2 * (cb + 16 * row + cs + N0) + o;
                const float Ax = xaF[lw];
                const float Bx = xbF[lw];
                float sn, cn;
                __sincosf((acc[j] + bo) * coef, &sn, &cn);
                __builtin_nontemporal_store(pk(Bx * cn - Ax * sn, Ax * cn + Bx * sn),
                                            &out[n * 2 + o]);
            }
        }
    }
}

extern "C" void kernel_launch(void* const* d_in, const int* in_sizes, int n_in,
                              void* d_out, int out_size, void* d_ws, size_t ws_size,
                              hipStream_t stream) {
    // Bind by size (robust): big arrays = x streams, 404 = W, 2 = b, 1 = power.
    const float* big[2] = {nullptr, nullptr};
    const float* W = nullptr; const float* b = nullptr; const float* power = nullptr;
    int nbig = 0;
    for (int i = 0; i < n_in; ++i) {
        const float* p = (const float*)d_in[i];
        const int sz = in_sizes[i];
        if (sz == NFFT * NMODES)       { if (nbig < 2) big[nbig++] = p; }
        else if (sz == NTAPS * NMODES * NMODES) { W = p; }
        else if (sz == NMODES)         { b = p; }
        else if (sz == 1)              { power = p; }
    }

    unsigned* out = (unsigned*)d_out;
    nl_kernel<<<NT, BLOCK, 0, stream>>>(big[0], big[1], W, b, power, out);
}